// Round 12
// baseline (863.830 us; speedup 1.0000x reference)
//
#include <hip/hip_runtime.h>
#include <hip/hip_bf16.h>

#define B_SZ   4096
#define S_LEN  200
#define EMB    300
#define TAGS   2

// ---------------------------------------------------------------------------
// Kernel 1: pooled[b][d] = mean_t emb[x[b][t]][d]
// Round-8 version (measured best): one block (4 waves) per batch row, wave w
// owns tokens t = w, w+4, ...; lane l loads float4 at dim 4l; lanes 0..10
// also cover dims 256..299. Compiler pipelines the loads (MLP sufficient at
// 32 waves/CU); explicit load batching regressed (R9: +28us, VGPR pressure).
// ---------------------------------------------------------------------------
__global__ __launch_bounds__(256)
void gather_mean_kernel(const int* __restrict__ x,
                        const float* __restrict__ emb,
                        float* __restrict__ pooled) {
    const int b    = blockIdx.x;
    const int tid  = threadIdx.x;
    const int wave = tid >> 6;
    const int lane = tid & 63;

    __shared__ int   ids[S_LEN];
    __shared__ float part[4][EMB + 4];   // row stride 304 floats (16B aligned)

    if (tid < S_LEN) ids[tid] = x[b * S_LEN + tid];
    __syncthreads();

    float4 acc0 = make_float4(0.f, 0.f, 0.f, 0.f);
    float4 acc1 = make_float4(0.f, 0.f, 0.f, 0.f);
    const bool has2 = (lane < (EMB - 256 + 3) / 4);   // lanes 0..10

#pragma unroll 2
    for (int i = 0; i < S_LEN / 4; ++i) {
        const int  t    = wave + 4 * i;
        const long base = (long)ids[t] * EMB;
        const float4 v0 = *(const float4*)&emb[base + 4 * lane];
        acc0.x += v0.x; acc0.y += v0.y; acc0.z += v0.z; acc0.w += v0.w;
        if (has2) {
            const float4 v1 = *(const float4*)&emb[base + 256 + 4 * lane];
            acc1.x += v1.x; acc1.y += v1.y; acc1.z += v1.z; acc1.w += v1.w;
        }
    }

    *(float4*)&part[wave][4 * lane] = acc0;
    if (has2) *(float4*)&part[wave][256 + 4 * lane] = acc1;
    __syncthreads();

    const float inv = 1.0f / (float)S_LEN;
    {
        const float s = part[0][tid] + part[1][tid] + part[2][tid] + part[3][tid];
        pooled[(long)b * EMB + tid] = s * inv;
    }
    if (tid < EMB - 256) {
        const int d = 256 + tid;
        const float s = part[0][d] + part[1][d] + part[2][d] + part[3][d];
        pooled[(long)b * EMB + d] = s * inv;
    }
}

// ---------------------------------------------------------------------------
// Kernels 2/3: C = relu(A @ W^T)   A:[M][K] row-major, W:[N][K] row-major
// 64x64 tile, BK=16, 256 threads (4 waves), 4x4 register micro-tile.
// k-major LDS ([BK][stride 68]): fragment reads are 2x ds_read_b128 per
// k-step feeding 16 FMA (compute-bound; was b128+b64 per 8 FMA at 4x2).
// Each thread stages one float4 of A and one of W per K-tile.
// ---------------------------------------------------------------------------
#define BM   64
#define BN   64
#define BK   16
#define LDST 68   // 68 % 32 == 4: staging writes 2-way (free), reads clean

template <bool RELU>
__global__ __launch_bounds__(256)
void gemm_tn_kernel(const float* __restrict__ A,
                    const float* __restrict__ W,
                    float* __restrict__ C,
                    int M, int N, int K) {
    __shared__ float As[BK][LDST];
    __shared__ float Ws[BK][LDST];

    const int tid = threadIdx.x;
    const int tx  = tid & 15;        // n-group: 4 cols each
    const int ty  = tid >> 4;        // m-group: 4 rows each (0..15)
    const int m0  = blockIdx.x * BM;
    const int n0  = blockIdx.y * BN;

    const int sr = tid >> 2;         // 0..63 tile row
    const int sc = (tid & 3) * 4;    // 0,4,8,12 k-offset

    float acc[4][4] = {};

    for (int k0 = 0; k0 < K; k0 += BK) {
        const int gk = k0 + sc;
        // ---- stage A tile (transposed into k-major LDS) ----
        {
            float4 v = make_float4(0.f, 0.f, 0.f, 0.f);
            const long off = (long)(m0 + sr) * K + gk;
            if (gk + 3 < K) {
                v = *(const float4*)&A[off];
            } else {
                if (gk + 0 < K) v.x = A[off + 0];
                if (gk + 1 < K) v.y = A[off + 1];
                if (gk + 2 < K) v.z = A[off + 2];
                if (gk + 3 < K) v.w = A[off + 3];
            }
            As[sc + 0][sr] = v.x;
            As[sc + 1][sr] = v.y;
            As[sc + 2][sr] = v.z;
            As[sc + 3][sr] = v.w;
        }
        // ---- stage W tile ----
        {
            float4 v = make_float4(0.f, 0.f, 0.f, 0.f);
            const int gn = n0 + sr;
            if (gn < N) {
                const long off = (long)gn * K + gk;
                if (gk + 3 < K) {
                    v = *(const float4*)&W[off];
                } else {
                    if (gk + 0 < K) v.x = W[off + 0];
                    if (gk + 1 < K) v.y = W[off + 1];
                    if (gk + 2 < K) v.z = W[off + 2];
                    if (gk + 3 < K) v.w = W[off + 3];
                }
            }
            Ws[sc + 0][sr] = v.x;
            Ws[sc + 1][sr] = v.y;
            Ws[sc + 2][sr] = v.z;
            Ws[sc + 3][sr] = v.w;
        }
        __syncthreads();

#pragma unroll
        for (int kk = 0; kk < BK; ++kk) {
            const float4 a  = *(const float4*)&As[kk][ty * 4];
            const float4 bb = *(const float4*)&Ws[kk][tx * 4];
#pragma unroll
            for (int i = 0; i < 4; ++i) {
                const float ai = (i == 0) ? a.x : (i == 1) ? a.y : (i == 2) ? a.z : a.w;
                acc[i][0] = fmaf(ai, bb.x, acc[i][0]);
                acc[i][1] = fmaf(ai, bb.y, acc[i][1]);
                acc[i][2] = fmaf(ai, bb.z, acc[i][2]);
                acc[i][3] = fmaf(ai, bb.w, acc[i][3]);
            }
        }
        __syncthreads();
    }

    // ---- epilogue: coalesced float4 stores (N % 4 == 0, row base aligned) ----
    const int gn0 = n0 + tx * 4;
#pragma unroll
    for (int i = 0; i < 4; ++i) {
        const int gm = m0 + ty * 4 + i;            // M % 64 == 0: always valid
        if (gn0 + 3 < N) {
            float4 v;
            v.x = RELU ? fmaxf(acc[i][0], 0.f) : acc[i][0];
            v.y = RELU ? fmaxf(acc[i][1], 0.f) : acc[i][1];
            v.z = RELU ? fmaxf(acc[i][2], 0.f) : acc[i][2];
            v.w = RELU ? fmaxf(acc[i][3], 0.f) : acc[i][3];
            *(float4*)&C[(long)gm * N + gn0] = v;
        } else {
#pragma unroll
            for (int j = 0; j < 4; ++j) {
                const int gn = gn0 + j;
                if (gn < N) {
                    float v = acc[i][j];
                    if (RELU) v = fmaxf(v, 0.f);
                    C[(long)gm * N + gn] = v;
                }
            }
        }
    }
}

// ---------------------------------------------------------------------------
// Kernel 4: out[b][t] = sum_k H[b][k] * w3[t][k]   (t = 0,1)
// one wave per row, shuffle reduce
// ---------------------------------------------------------------------------
__global__ __launch_bounds__(256)
void final_kernel(const float* __restrict__ H,
                  const float* __restrict__ w3,
                  float* __restrict__ out) {
    const int wave = threadIdx.x >> 6;       // 0..3
    const int lane = threadIdx.x & 63;
    const int row  = blockIdx.x * 4 + wave;
    if (row >= B_SZ) return;

    float a0 = 0.f, a1 = 0.f;
    for (int k = lane; k < EMB; k += 64) {
        const float h = H[(long)row * EMB + k];
        a0 += h * w3[k];
        a1 += h * w3[EMB + k];
    }
#pragma unroll
    for (int off = 32; off > 0; off >>= 1) {
        a0 += __shfl_down(a0, off);
        a1 += __shfl_down(a1, off);
    }
    if (lane == 0) {
        out[row * TAGS + 0] = a0;
        out[row * TAGS + 1] = a1;
    }
}

// ---------------------------------------------------------------------------
extern "C" void kernel_launch(void* const* d_in, const int* in_sizes, int n_in,
                              void* d_out, int out_size, void* d_ws, size_t ws_size,
                              hipStream_t stream) {
    const int*   x   = (const int*)d_in[0];
    const float* emb = (const float*)d_in[1];
    const float* w1  = (const float*)d_in[2];
    const float* w2  = (const float*)d_in[3];
    const float* w3  = (const float*)d_in[4];
    float*       out = (float*)d_out;

    float* pooled = (float*)d_ws;                       // [4096][300]
    float* h1     = pooled + (long)B_SZ * EMB;          // [4096][300]
    // h2 reuses the pooled buffer (pooled is dead after layer 1)

    gather_mean_kernel<<<B_SZ, 256, 0, stream>>>(x, emb, pooled);

    dim3 gemm_grid(B_SZ / BM, (EMB + BN - 1) / BN);     // 64 x 5
    gemm_tn_kernel<true><<<gemm_grid, 256, 0, stream>>>(pooled, w1, h1, B_SZ, EMB, EMB);
    gemm_tn_kernel<true><<<gemm_grid, 256, 0, stream>>>(h1, w2, pooled, B_SZ, EMB, EMB);

    final_kernel<<<(B_SZ + 3) / 4, 256, 0, stream>>>(pooled, w3, out);
}